// Round 1
// baseline (119.846 us; speedup 1.0000x reference)
//
#include <hip/hip_runtime.h>
#include <hip/hip_bf16.h>

// Problem constants (from reference)
#define B_SENT 128
#define L_TOK  256
#define D_DIM  1024

// Tile config
#define TM 64               // tokens per block (L_TOK/TM = 4 tiles per sentence, exact)
#define BK 64               // K-step
#define LDS_PAD 8           // +8 bf16 pad -> row stride 144B -> ~2-way bank aliasing (free)
#define LDS_STRIDE (BK + LDS_PAD)

typedef __attribute__((ext_vector_type(8))) short bf16x8;
typedef __attribute__((ext_vector_type(4))) float f32x4;
typedef __attribute__((ext_vector_type(4))) unsigned short ushort4v;

__device__ __forceinline__ unsigned short f2bf(float f) {
    __hip_bfloat16 h = __float2bfloat16(f);
    return __builtin_bit_cast(unsigned short, h);
}

// numerically stable softplus
__device__ __forceinline__ float softplus_f(float x) {
    float ax = fabsf(x);
    return fmaxf(x, 0.0f) + log1pf(__expf(-ax));
}

__global__ __launch_bounds__(256) void mi_gemm_kernel(
    const float* __restrict__ tok0, const float* __restrict__ tok1,
    const float* __restrict__ glob0, const float* __restrict__ glob1,
    const int* __restrict__ len0, const int* __restrict__ len1,
    float* __restrict__ acc_ws)
{
    const int side = blockIdx.y;
    const float* tok  = side ? tok1  : tok0;
    const float* glob = side ? glob1 : glob0;
    const int*   len  = side ? len1  : len0;

    const int bx     = blockIdx.x;        // 0..511
    const int tb     = bx * TM;           // global token base
    const int b_sent = tb / L_TOK;        // whole tile lies in one sentence
    const int vstart = tb % L_TOK;

    const int len_b = max(1, len[b_sent]);
    const int count = len_b - vstart;     // # valid rows in this tile
    if (count <= 0) return;               // tile fully masked: contributes exactly 0

    __shared__ short As[TM][LDS_STRIDE];
    __shared__ short Gs[B_SENT][LDS_STRIDE];
    __shared__ float sred[8];

    const int tid  = threadIdx.x;
    const int wave = tid >> 6;
    const int lane = tid & 63;
    const int lrow = lane & 15;           // row/col within 16 fragment
    const int kgrp = lane >> 4;           // k-group of 8

    f32x4 acc[8];
#pragma unroll
    for (int n = 0; n < 8; ++n) acc[n] = (f32x4){0.f, 0.f, 0.f, 0.f};

    for (int kb = 0; kb < D_DIM / BK; ++kb) {
        const int k0 = kb * BK;
        __syncthreads();   // previous compute done before overwriting LDS

        // --- stage A tile: 64 rows x 64 f32 -> bf16 LDS. 1024 float4 slots, 4/thread
#pragma unroll
        for (int i = 0; i < 4; ++i) {
            int s   = i * 256 + tid;
            int row = s >> 4;
            int c4  = (s & 15) * 4;
            const float4 v = *reinterpret_cast<const float4*>(
                &tok[(size_t)(tb + row) * D_DIM + k0 + c4]);
            ushort4v u;
            u[0] = f2bf(v.x); u[1] = f2bf(v.y); u[2] = f2bf(v.z); u[3] = f2bf(v.w);
            *reinterpret_cast<ushort4v*>(&As[row][c4]) = u;
        }
        // --- stage G tile: 128 rows x 64 f32 -> bf16 LDS. 2048 slots, 8/thread
#pragma unroll
        for (int i = 0; i < 8; ++i) {
            int s   = i * 256 + tid;
            int row = s >> 4;
            int c4  = (s & 15) * 4;
            const float4 v = *reinterpret_cast<const float4*>(
                &glob[(size_t)row * D_DIM + k0 + c4]);
            ushort4v u;
            u[0] = f2bf(v.x); u[1] = f2bf(v.y); u[2] = f2bf(v.z); u[3] = f2bf(v.w);
            *reinterpret_cast<ushort4v*>(&Gs[row][c4]) = u;
        }
        __syncthreads();

        // --- compute: wave owns 16 tokens x 128 globals
#pragma unroll
        for (int ks = 0; ks < 2; ++ks) {
            const int kofs = ks * 32 + kgrp * 8;
            bf16x8 a = *reinterpret_cast<const bf16x8*>(&As[wave * 16 + lrow][kofs]);
#pragma unroll
            for (int n = 0; n < 8; ++n) {
                bf16x8 b = *reinterpret_cast<const bf16x8*>(&Gs[n * 16 + lrow][kofs]);
                acc[n] = __builtin_amdgcn_mfma_f32_16x16x32_bf16(a, b, acc[n], 0, 0, 0);
            }
        }
    }

    // --- epilogue: masked softplus reduction
    // C/D layout (m89): col = lane&15, row = (lane>>4)*4 + j (within 16-row fragment)
    float ep = 0.f, en = 0.f;
    const int rbase = wave * 16 + kgrp * 4;
#pragma unroll
    for (int n = 0; n < 8; ++n) {
        const int g = n * 16 + lrow;
#pragma unroll
        for (int j = 0; j < 4; ++j) {
            const int rl = rbase + j;      // local token row 0..63
            if (rl < count) {
                float res = acc[n][j];
                float sp  = softplus_f(res);
                if (g == b_sent) ep += res - sp;   // -softplus(-res)
                else             en += sp;         // softplus(-res)+res
            }
        }
    }

    // wave shuffle reduce (64 lanes)
#pragma unroll
    for (int off = 32; off; off >>= 1) {
        ep += __shfl_down(ep, off);
        en += __shfl_down(en, off);
    }
    if (lane == 0) { sred[wave * 2] = ep; sred[wave * 2 + 1] = en; }
    __syncthreads();
    if (tid == 0) {
        float tep = sred[0] + sred[2] + sred[4] + sred[6];
        float ten = sred[1] + sred[3] + sred[5] + sred[7];
        atomicAdd(&acc_ws[side * 2 + 0], tep);
        atomicAdd(&acc_ws[side * 2 + 1], ten);
    }
}

__global__ void mi_finalize_kernel(const int* __restrict__ len0,
                                   const int* __restrict__ len1,
                                   const float* __restrict__ acc_ws,
                                   float* __restrict__ out)
{
    const int lane = threadIdx.x;  // 64 threads, 1 wave
    int s0 = 0, s1 = 0;
    for (int i = lane; i < B_SENT; i += 64) {
        s0 += max(1, len0[i]);
        s1 += max(1, len1[i]);
    }
#pragma unroll
    for (int off = 32; off; off >>= 1) {
        s0 += __shfl_down(s0, off);
        s1 += __shfl_down(s1, off);
    }
    if (lane == 0) {
        const float num_nodes = (float)(s0 + s1);
        const float ep = acc_ws[0] + acc_ws[2];
        const float en = acc_ws[1] + acc_ws[3];
        const float e_pos = ep / num_nodes;
        const float e_neg = en / (num_nodes * (float)(B_SENT - 1));
        out[0] = e_neg - e_pos;
        out[1] = ((float)s0 / (float)B_SENT + (float)s1 / (float)B_SENT) * 0.5f;
    }
}

extern "C" void kernel_launch(void* const* d_in, const int* in_sizes, int n_in,
                              void* d_out, int out_size, void* d_ws, size_t ws_size,
                              hipStream_t stream) {
    const float* tok0  = (const float*)d_in[0];
    const float* tok1  = (const float*)d_in[1];
    const float* glob0 = (const float*)d_in[2];
    const float* glob1 = (const float*)d_in[3];
    const int*   len0  = (const int*)d_in[4];
    const int*   len1  = (const int*)d_in[5];
    float* out = (float*)d_out;
    float* acc = (float*)d_ws;

    hipMemsetAsync(acc, 0, 4 * sizeof(float), stream);

    dim3 grid(32768 / TM, 2);   // 512 token-tiles x 2 sides
    mi_gemm_kernel<<<grid, 256, 0, stream>>>(tok0, tok1, glob0, glob1, len0, len1, acc);
    mi_finalize_kernel<<<1, 64, 0, stream>>>(len0, len1, acc, out);
}

// Round 2
// 92.650 us; speedup vs baseline: 1.2935x; 1.2935x over previous
//
#include <hip/hip_runtime.h>
#include <hip/hip_bf16.h>

#define B_SENT 128
#define L_TOK  256
#define D_DIM  1024
#define TM     32          // tokens per block (8 tiles per sentence)

typedef __attribute__((ext_vector_type(8))) short bf16x8;
typedef __attribute__((ext_vector_type(4))) float f32x4;

__device__ __forceinline__ unsigned short f2bf(float f) {
    return __builtin_bit_cast(unsigned short, __float2bfloat16(f));
}
__device__ __forceinline__ float softplus_f(float x) {
    float ax = fabsf(x);
    return fmaxf(x, 0.0f) + __logf(1.0f + __expf(-ax));
}

// ---------------------------------------------------------------------------
// Pre-pack glob (f32) into bf16 MFMA B-fragment order:
// packed[(((side*16 + kb)*2 + ks)*8 + n)*64 + lane] = 8 bf16 =
//   glob[side][n*16 + (lane&15)][kb*64 + ks*32 + (lane>>4)*8 .. +8]
// Total 2*16*2*8*64*16B = 512 KB, L2-resident.
// ---------------------------------------------------------------------------
__global__ __launch_bounds__(256) void pack_g_kernel(
    const float* __restrict__ g0, const float* __restrict__ g1,
    short* __restrict__ packed)
{
    const int idx  = blockIdx.x * 256 + threadIdx.x;   // 0..32767
    const int lane = idx & 63;
    const int n    = (idx >> 6) & 7;
    const int ks   = (idx >> 9) & 1;
    const int kb   = (idx >> 10) & 15;
    const int side = idx >> 14;
    const int row  = n * 16 + (lane & 15);
    const int col  = kb * 64 + ks * 32 + (lane >> 4) * 8;
    const float* g = side ? g1 : g0;
    const float4 v0 = *reinterpret_cast<const float4*>(&g[(size_t)row * D_DIM + col]);
    const float4 v1 = *reinterpret_cast<const float4*>(&g[(size_t)row * D_DIM + col + 4]);
    bf16x8 u;
    u[0] = (short)f2bf(v0.x); u[1] = (short)f2bf(v0.y);
    u[2] = (short)f2bf(v0.z); u[3] = (short)f2bf(v0.w);
    u[4] = (short)f2bf(v1.x); u[5] = (short)f2bf(v1.y);
    u[6] = (short)f2bf(v1.z); u[7] = (short)f2bf(v1.w);
    *reinterpret_cast<bf16x8*>(&packed[(size_t)idx * 8]) = u;
}

// ---------------------------------------------------------------------------
// Main: grid (1024, 2). Block = 4 waves: wave&1 = token-half (16 rows),
// wave>>1 = K-half (512 of 1024). No LDS/barriers in the main loop.
// ---------------------------------------------------------------------------
__global__ __launch_bounds__(256) void mi_main_kernel(
    const float* __restrict__ tok0, const float* __restrict__ tok1,
    const int* __restrict__ len0, const int* __restrict__ len1,
    const short* __restrict__ packed, float* __restrict__ acc_ws)
{
    const int side = blockIdx.y;
    const float* tok = side ? tok1 : tok0;
    const int*   len = side ? len1 : len0;

    const int bx     = blockIdx.x;          // 0..1023
    const int tb     = bx * TM;
    const int b_sent = bx >> 3;             // 8 tiles per sentence
    const int vstart = (bx & 7) * TM;
    const int count  = max(1, len[b_sent]) - vstart;
    if (count <= 0) return;                 // whole-block early exit

    const int tid   = threadIdx.x;
    const int wave  = tid >> 6;
    const int lane  = tid & 63;
    const int thalf = wave & 1;             // token half
    const int khalf = wave >> 1;            // K half
    const int lrow  = lane & 15;
    const int kgrp  = lane >> 4;

    const int  arow   = thalf * 16 + lrow;          // local token row for A frag
    const bool avalid = arow < count;
    const float* aptr = tok + (size_t)(tb + arow) * D_DIM + khalf * 512 + kgrp * 8;
    // B fragments: this wave's K-half spans kb_global = khalf*8 .. +8
    const short* bbase = packed
        + ((size_t)side * 16 + (size_t)khalf * 8) * 8192 + (size_t)lane * 8;

    f32x4 acc[8];
#pragma unroll
    for (int n = 0; n < 8; ++n) acc[n] = (f32x4){0.f, 0.f, 0.f, 0.f};

#pragma unroll 2
    for (int kb = 0; kb < 8; ++kb) {
        const float* ap = aptr + kb * 64;
        float4 a00, a01, a10, a11;
        if (avalid) {
            a00 = *reinterpret_cast<const float4*>(ap);
            a01 = *reinterpret_cast<const float4*>(ap + 4);
            a10 = *reinterpret_cast<const float4*>(ap + 32);
            a11 = *reinterpret_cast<const float4*>(ap + 36);
        } else {
            a00 = a01 = a10 = a11 = (float4){0.f, 0.f, 0.f, 0.f};
        }
        bf16x8 af0, af1;
        af0[0] = (short)f2bf(a00.x); af0[1] = (short)f2bf(a00.y);
        af0[2] = (short)f2bf(a00.z); af0[3] = (short)f2bf(a00.w);
        af0[4] = (short)f2bf(a01.x); af0[5] = (short)f2bf(a01.y);
        af0[6] = (short)f2bf(a01.z); af0[7] = (short)f2bf(a01.w);
        af1[0] = (short)f2bf(a10.x); af1[1] = (short)f2bf(a10.y);
        af1[2] = (short)f2bf(a10.z); af1[3] = (short)f2bf(a10.w);
        af1[4] = (short)f2bf(a11.x); af1[5] = (short)f2bf(a11.y);
        af1[6] = (short)f2bf(a11.z); af1[7] = (short)f2bf(a11.w);

        const short* bp = bbase + (size_t)kb * 8192;
#pragma unroll
        for (int n = 0; n < 8; ++n) {
            bf16x8 b = *reinterpret_cast<const bf16x8*>(bp + n * 512);
            acc[n] = __builtin_amdgcn_mfma_f32_16x16x32_bf16(af0, b, acc[n], 0, 0, 0);
        }
#pragma unroll
        for (int n = 0; n < 8; ++n) {
            bf16x8 b = *reinterpret_cast<const bf16x8*>(bp + 4096 + n * 512);
            acc[n] = __builtin_amdgcn_mfma_f32_16x16x32_bf16(af1, b, acc[n], 0, 0, 0);
        }
    }

    // --- combine K-halves through LDS (single barrier) ---
    __shared__ f32x4 lacc[2][64][8];    // 16 KB
    __shared__ float sred[8];
    if (khalf == 1) {
#pragma unroll
        for (int n = 0; n < 8; ++n) lacc[thalf][lane][n] = acc[n];
    }
    __syncthreads();

    float ep = 0.f, en = 0.f;
    if (khalf == 0) {
#pragma unroll
        for (int n = 0; n < 8; ++n) {
            f32x4 o = lacc[thalf][lane][n];
            acc[n][0] += o[0]; acc[n][1] += o[1];
            acc[n][2] += o[2]; acc[n][3] += o[3];
        }
        // C/D layout: col = lane&15 (global idx), row = kgrp*4 + j (token)
#pragma unroll
        for (int n = 0; n < 8; ++n) {
            const int g = n * 16 + lrow;
#pragma unroll
            for (int j = 0; j < 4; ++j) {
                const int rl = thalf * 16 + kgrp * 4 + j;
                if (rl < count) {
                    float res = acc[n][j];
                    float sp  = softplus_f(res);
                    if (g == b_sent) ep += res - sp;   // -softplus(-res)
                    else             en += sp;         // softplus(-res)+res
                }
            }
        }
    }

#pragma unroll
    for (int off = 32; off; off >>= 1) {
        ep += __shfl_down(ep, off);
        en += __shfl_down(en, off);
    }
    if (lane == 0) { sred[wave * 2] = ep; sred[wave * 2 + 1] = en; }
    __syncthreads();
    if (tid == 0) {
        float tep = sred[0] + sred[2] + sred[4] + sred[6];
        float ten = sred[1] + sred[3] + sred[5] + sred[7];
        atomicAdd(&acc_ws[side * 2 + 0], tep);
        atomicAdd(&acc_ws[side * 2 + 1], ten);
    }
}

__global__ void mi_finalize_kernel(const int* __restrict__ len0,
                                   const int* __restrict__ len1,
                                   const float* __restrict__ acc_ws,
                                   float* __restrict__ out)
{
    const int lane = threadIdx.x;   // 1 wave
    int s0 = 0, s1 = 0;
    for (int i = lane; i < B_SENT; i += 64) {
        s0 += max(1, len0[i]);
        s1 += max(1, len1[i]);
    }
#pragma unroll
    for (int off = 32; off; off >>= 1) {
        s0 += __shfl_down(s0, off);
        s1 += __shfl_down(s1, off);
    }
    if (lane == 0) {
        const float num_nodes = (float)(s0 + s1);
        const float ep = acc_ws[0] + acc_ws[2];
        const float en = acc_ws[1] + acc_ws[3];
        out[0] = en / (num_nodes * (float)(B_SENT - 1)) - ep / num_nodes;
        out[1] = ((float)s0 + (float)s1) / (2.0f * (float)B_SENT);
    }
}

extern "C" void kernel_launch(void* const* d_in, const int* in_sizes, int n_in,
                              void* d_out, int out_size, void* d_ws, size_t ws_size,
                              hipStream_t stream) {
    const float* tok0  = (const float*)d_in[0];
    const float* tok1  = (const float*)d_in[1];
    const float* glob0 = (const float*)d_in[2];
    const float* glob1 = (const float*)d_in[3];
    const int*   len0  = (const int*)d_in[4];
    const int*   len1  = (const int*)d_in[5];
    float* out = (float*)d_out;

    float* acc    = (float*)d_ws;                       // 4 floats @ offset 0
    short* packed = (short*)((char*)d_ws + 256);        // 512 KB bf16 fragments

    hipMemsetAsync(d_ws, 0, 256, stream);
    pack_g_kernel<<<128, 256, 0, stream>>>(glob0, glob1, packed);

    dim3 grid(32768 / TM, 2);   // 1024 token-tiles x 2 sides
    mi_main_kernel<<<grid, 256, 0, stream>>>(tok0, tok1, len0, len1, packed, acc);
    mi_finalize_kernel<<<1, 64, 0, stream>>>(len0, len1, acc, out);
}

// Round 3
// 87.634 us; speedup vs baseline: 1.3676x; 1.0572x over previous
//
#include <hip/hip_runtime.h>
#include <hip/hip_bf16.h>

#define B_SENT 128
#define L_TOK  256
#define D_DIM  1024
#define TM     32          // tokens per block (8 tiles per sentence)

typedef __attribute__((ext_vector_type(8))) short bf16x8;
typedef __attribute__((ext_vector_type(4))) float f32x4;

__device__ __forceinline__ unsigned short f2bf(float f) {
    return __builtin_bit_cast(unsigned short, __float2bfloat16(f));
}
__device__ __forceinline__ float softplus_f(float x) {
    float ax = fabsf(x);
    return fmaxf(x, 0.0f) + __logf(1.0f + __expf(-ax));
}
__device__ __forceinline__ bf16x8 cvt8(const float4& lo, const float4& hi) {
    bf16x8 u;
    u[0] = (short)f2bf(lo.x); u[1] = (short)f2bf(lo.y);
    u[2] = (short)f2bf(lo.z); u[3] = (short)f2bf(lo.w);
    u[4] = (short)f2bf(hi.x); u[5] = (short)f2bf(hi.y);
    u[6] = (short)f2bf(hi.z); u[7] = (short)f2bf(hi.w);
    return u;
}

// ---------------------------------------------------------------------------
// Pre-pack glob (f32) into bf16 MFMA B-fragment order (512 KB, L2-resident):
// packed[(((side*16 + kb)*2 + ks)*8 + n)*64 + lane][0..7] =
//   glob[side][n*16 + (lane&15)][kb*64 + ks*32 + (lane>>4)*8 .. +8]
// ---------------------------------------------------------------------------
__global__ __launch_bounds__(256) void pack_g_kernel(
    const float* __restrict__ g0, const float* __restrict__ g1,
    short* __restrict__ packed)
{
    const int idx  = blockIdx.x * 256 + threadIdx.x;   // 0..32767
    const int lane = idx & 63;
    const int n    = (idx >> 6) & 7;
    const int ks   = (idx >> 9) & 1;
    const int kb   = (idx >> 10) & 15;
    const int side = idx >> 14;
    const int row  = n * 16 + (lane & 15);
    const int col  = kb * 64 + ks * 32 + (lane >> 4) * 8;
    const float* g = side ? g1 : g0;
    const float4 v0 = *reinterpret_cast<const float4*>(&g[(size_t)row * D_DIM + col]);
    const float4 v1 = *reinterpret_cast<const float4*>(&g[(size_t)row * D_DIM + col + 4]);
    *reinterpret_cast<bf16x8*>(&packed[(size_t)idx * 8]) = cvt8(v0, v1);
}

// ---------------------------------------------------------------------------
// Main: grid (1024, 2). 4 waves: wave&1 = token-half, wave>>1 = K-half.
// Software-pipelined: A(kb+1) + B-groups prefetched into registers.
// ---------------------------------------------------------------------------
__global__ __launch_bounds__(256, 4) void mi_main_kernel(
    const float* __restrict__ tok0, const float* __restrict__ tok1,
    const int* __restrict__ len0, const int* __restrict__ len1,
    const short* __restrict__ packed, float* __restrict__ acc_ws)
{
    const int side = blockIdx.y;
    const float* tok = side ? tok1 : tok0;
    const int*   len = side ? len1 : len0;

    const int bx     = blockIdx.x;          // 0..1023
    const int tb     = bx * TM;
    const int b_sent = bx >> 3;             // 8 tiles per sentence
    const int vstart = (bx & 7) * TM;
    const int count  = max(1, len[b_sent]) - vstart;
    if (count <= 0) return;                 // fully masked tile: contributes 0

    const int tid   = threadIdx.x;
    const int wave  = tid >> 6;
    const int lane  = tid & 63;
    const int thalf = wave & 1;             // token half
    const int khalf = wave >> 1;            // K half
    const int lrow  = lane & 15;
    const int kgrp  = lane >> 4;

    const int  arow   = thalf * 16 + lrow;
    const bool avalid = arow < count;
    const float* aptr = tok + (size_t)(tb + arow) * D_DIM + khalf * 512 + kgrp * 8;
    const short* bbase = packed
        + ((size_t)side * 16 + (size_t)khalf * 8) * 8192 + (size_t)lane * 8;

    f32x4 acc[8];
#pragma unroll
    for (int n = 0; n < 8; ++n) acc[n] = (f32x4){0.f, 0.f, 0.f, 0.f};

    const float4 z4 = (float4){0.f, 0.f, 0.f, 0.f};
    float4 Ac0, Ac1, Ac2, Ac3, An0, An1, An2, An3;

    // prologue: load kb=0
    if (avalid) {
        Ac0 = *reinterpret_cast<const float4*>(aptr);
        Ac1 = *reinterpret_cast<const float4*>(aptr + 4);
        Ac2 = *reinterpret_cast<const float4*>(aptr + 32);
        Ac3 = *reinterpret_cast<const float4*>(aptr + 36);
    } else { Ac0 = Ac1 = Ac2 = Ac3 = z4; }

#pragma unroll
    for (int kb = 0; kb < 8; ++kb) {
        // issue next A tile early (hides HBM/L3 latency under this iter's MFMAs)
        if (kb < 7) {
            const float* ap = aptr + (kb + 1) * 64;
            if (avalid) {
                An0 = *reinterpret_cast<const float4*>(ap);
                An1 = *reinterpret_cast<const float4*>(ap + 4);
                An2 = *reinterpret_cast<const float4*>(ap + 32);
                An3 = *reinterpret_cast<const float4*>(ap + 36);
            } else { An0 = An1 = An2 = An3 = z4; }
        }

        const short* bp = bbase + (size_t)kb * 8192;
        // prefetch B group 0 (8 L2-resident fragment loads in flight)
        bf16x8 b0[8];
#pragma unroll
        for (int n = 0; n < 8; ++n)
            b0[n] = *reinterpret_cast<const bf16x8*>(bp + n * 512);

        const bf16x8 af0 = cvt8(Ac0, Ac1);
        const bf16x8 af1 = cvt8(Ac2, Ac3);

#pragma unroll
        for (int n = 0; n < 8; ++n)
            acc[n] = __builtin_amdgcn_mfma_f32_16x16x32_bf16(af0, b0[n], acc[n], 0, 0, 0);
#pragma unroll
        for (int n = 0; n < 8; ++n) {
            bf16x8 b = *reinterpret_cast<const bf16x8*>(bp + 4096 + n * 512);
            acc[n] = __builtin_amdgcn_mfma_f32_16x16x32_bf16(af1, b, acc[n], 0, 0, 0);
        }

        Ac0 = An0; Ac1 = An1; Ac2 = An2; Ac3 = An3;
    }

    // --- combine K-halves through LDS (single barrier) ---
    __shared__ f32x4 lacc[2][64][8];    // 16 KB
    __shared__ float sred[8];
    if (khalf == 1) {
#pragma unroll
        for (int n = 0; n < 8; ++n) lacc[thalf][lane][n] = acc[n];
    }
    __syncthreads();

    float ep = 0.f, en = 0.f;
    if (khalf == 0) {
#pragma unroll
        for (int n = 0; n < 8; ++n) {
            f32x4 o = lacc[thalf][lane][n];
            acc[n][0] += o[0]; acc[n][1] += o[1];
            acc[n][2] += o[2]; acc[n][3] += o[3];
        }
        // C/D layout: col = lane&15 (global idx), row = kgrp*4 + j (token)
#pragma unroll
        for (int n = 0; n < 8; ++n) {
            const int g = n * 16 + lrow;
#pragma unroll
            for (int j = 0; j < 4; ++j) {
                const int rl = thalf * 16 + kgrp * 4 + j;
                if (rl < count) {
                    float res = acc[n][j];
                    float sp  = softplus_f(res);
                    if (g == b_sent) ep += res - sp;   // -softplus(-res)
                    else             en += sp;         // softplus(-res)+res
                }
            }
        }
    }

#pragma unroll
    for (int off = 32; off; off >>= 1) {
        ep += __shfl_down(ep, off);
        en += __shfl_down(en, off);
    }
    if (lane == 0) { sred[wave * 2] = ep; sred[wave * 2 + 1] = en; }
    __syncthreads();
    if (tid == 0) {
        float tep = sred[0] + sred[2] + sred[4] + sred[6];
        float ten = sred[1] + sred[3] + sred[5] + sred[7];
        atomicAdd(&acc_ws[side * 2 + 0], tep);
        atomicAdd(&acc_ws[side * 2 + 1], ten);
    }
}

__global__ void mi_finalize_kernel(const int* __restrict__ len0,
                                   const int* __restrict__ len1,
                                   const float* __restrict__ acc_ws,
                                   float* __restrict__ out)
{
    const int lane = threadIdx.x;   // 1 wave
    int s0 = 0, s1 = 0;
    for (int i = lane; i < B_SENT; i += 64) {
        s0 += max(1, len0[i]);
        s1 += max(1, len1[i]);
    }
#pragma unroll
    for (int off = 32; off; off >>= 1) {
        s0 += __shfl_down(s0, off);
        s1 += __shfl_down(s1, off);
    }
    if (lane == 0) {
        const float num_nodes = (float)(s0 + s1);
        const float ep = acc_ws[0] + acc_ws[2];
        const float en = acc_ws[1] + acc_ws[3];
        out[0] = en / (num_nodes * (float)(B_SENT - 1)) - ep / num_nodes;
        out[1] = ((float)s0 + (float)s1) / (2.0f * (float)B_SENT);
    }
}

extern "C" void kernel_launch(void* const* d_in, const int* in_sizes, int n_in,
                              void* d_out, int out_size, void* d_ws, size_t ws_size,
                              hipStream_t stream) {
    const float* tok0  = (const float*)d_in[0];
    const float* tok1  = (const float*)d_in[1];
    const float* glob0 = (const float*)d_in[2];
    const float* glob1 = (const float*)d_in[3];
    const int*   len0  = (const int*)d_in[4];
    const int*   len1  = (const int*)d_in[5];
    float* out = (float*)d_out;

    float* acc    = (float*)d_ws;                       // 4 floats @ offset 0
    short* packed = (short*)((char*)d_ws + 256);        // 512 KB bf16 fragments

    hipMemsetAsync(d_ws, 0, 256, stream);
    pack_g_kernel<<<128, 256, 0, stream>>>(glob0, glob1, packed);

    dim3 grid(32768 / TM, 2);   // 1024 token-tiles x 2 sides
    mi_main_kernel<<<grid, 256, 0, stream>>>(tok0, tok1, len0, len1, packed, acc);
    mi_finalize_kernel<<<1, 64, 0, stream>>>(len0, len1, acc, out);
}

// Round 4
// 58.664 us; speedup vs baseline: 2.0429x; 1.4938x over previous
//
#include <hip/hip_runtime.h>
#include <hip/hip_bf16.h>

#define B_SENT 128
#define L_TOK  256
#define D_DIM  1024
#define TM     64          // tokens per block (4 tiles per sentence)

typedef __attribute__((ext_vector_type(8))) short bf16x8;
typedef __attribute__((ext_vector_type(4))) float f32x4;

__device__ __forceinline__ unsigned short f2bf(float f) {
    return __builtin_bit_cast(unsigned short, __float2bfloat16(f));
}
__device__ __forceinline__ float softplus_f(float x) {
    float ax = fabsf(x);
    return fmaxf(x, 0.0f) + __logf(1.0f + __expf(-ax));
}
__device__ __forceinline__ bf16x8 cvt8(const float4& lo, const float4& hi) {
    bf16x8 u;
    u[0] = (short)f2bf(lo.x); u[1] = (short)f2bf(lo.y);
    u[2] = (short)f2bf(lo.z); u[3] = (short)f2bf(lo.w);
    u[4] = (short)f2bf(hi.x); u[5] = (short)f2bf(hi.y);
    u[6] = (short)f2bf(hi.z); u[7] = (short)f2bf(hi.w);
    return u;
}

// ---------------------------------------------------------------------------
// Pre-pack glob (f32) into bf16 MFMA B-fragment order (512 KB, L2-resident):
// for (side, kb) the 16 KB chunk holds frag (ks, n) at ((ks*8+n)*64+lane)*8
//   = glob[side][n*16 + (lane&15)][kb*64 + ks*32 + (lane>>4)*8 .. +8]
// ---------------------------------------------------------------------------
__global__ __launch_bounds__(256) void pack_g_kernel(
    const float* __restrict__ g0, const float* __restrict__ g1,
    short* __restrict__ packed)
{
    const int idx  = blockIdx.x * 256 + threadIdx.x;   // 0..32767
    const int lane = idx & 63;
    const int n    = (idx >> 6) & 7;
    const int ks   = (idx >> 9) & 1;
    const int kb   = (idx >> 10) & 15;
    const int side = idx >> 14;
    const int row  = n * 16 + (lane & 15);
    const int col  = kb * 64 + ks * 32 + (lane >> 4) * 8;
    const float* g = side ? g1 : g0;
    const float4 v0 = *reinterpret_cast<const float4*>(&g[(size_t)row * D_DIM + col]);
    const float4 v1 = *reinterpret_cast<const float4*>(&g[(size_t)row * D_DIM + col + 4]);
    *reinterpret_cast<bf16x8*>(&packed[(size_t)idx * 8]) = cvt8(v0, v1);
}

// ---------------------------------------------------------------------------
// Main: canonical dbuf-LDS GEMM. Block = 64 tokens x 128 sentences, 4 waves
// (wave = 16 token rows). B-panel staged once/block/K-step into LDS (dbuf),
// A direct global->reg with 1-deep prefetch. One barrier per K-step.
// ---------------------------------------------------------------------------
__global__ __launch_bounds__(256, 4) void mi_main_kernel(
    const float* __restrict__ tok0, const float* __restrict__ tok1,
    const int* __restrict__ len0, const int* __restrict__ len1,
    const short* __restrict__ packed, float* __restrict__ acc_ws)
{
    const int side = blockIdx.y;
    const float* tok = side ? tok1 : tok0;
    const int*   len = side ? len1 : len0;

    const int tile   = blockIdx.x;       // 0..511
    const int tb     = tile * TM;
    const int b_sent = tile >> 2;        // 4 tiles per sentence
    const int vstart = (tile & 3) * TM;
    const int count  = max(1, len[b_sent]) - vstart;
    if (count <= 0) return;              // whole-block early exit (uniform)

    const int tid  = threadIdx.x;
    const int wave = tid >> 6;
    const int lane = tid & 63;
    const int lrow = lane & 15;
    const int kgrp = lane >> 4;

    __shared__ short Bs[2][8192];        // 2 x 16 KB B-panel double buffer
    __shared__ float sred[8];

    const short* bsrc = packed + (size_t)(side * 16) * 8192;
    const int  arow   = wave * 16 + lrow;
    const bool avalid = arow < count;    // loop-invariant per lane
    const float* aptr = tok + (size_t)(tb + arow) * D_DIM + kgrp * 8;

    f32x4 acc[8];
#pragma unroll
    for (int n = 0; n < 8; ++n) acc[n] = (f32x4){0.f, 0.f, 0.f, 0.f};

    const float4 z4 = (float4){0.f, 0.f, 0.f, 0.f};
    float4 Ac0 = z4, Ac1 = z4, Ac2 = z4, Ac3 = z4;

    // ---- prologue: stage kb=0 B-panel + load kb=0 A ----
    {
        const short* bp = bsrc + tid * 8;
#pragma unroll
        for (int i = 0; i < 4; ++i)
            *reinterpret_cast<bf16x8*>(&Bs[0][i * 2048 + tid * 8]) =
                *reinterpret_cast<const bf16x8*>(bp + i * 2048);
        if (avalid) {
            Ac0 = *reinterpret_cast<const float4*>(aptr);
            Ac1 = *reinterpret_cast<const float4*>(aptr + 4);
            Ac2 = *reinterpret_cast<const float4*>(aptr + 32);
            Ac3 = *reinterpret_cast<const float4*>(aptr + 36);
        }
    }
    __syncthreads();

    auto compute = [&](int buf, const bf16x8& af0, const bf16x8& af1) {
#pragma unroll
        for (int n = 0; n < 8; ++n) {
            bf16x8 b = *reinterpret_cast<const bf16x8*>(&Bs[buf][(n * 64 + lane) * 8]);
            acc[n] = __builtin_amdgcn_mfma_f32_16x16x32_bf16(af0, b, acc[n], 0, 0, 0);
        }
#pragma unroll
        for (int n = 0; n < 8; ++n) {
            bf16x8 b = *reinterpret_cast<const bf16x8*>(&Bs[buf][((8 + n) * 64 + lane) * 8]);
            acc[n] = __builtin_amdgcn_mfma_f32_16x16x32_bf16(af1, b, acc[n], 0, 0, 0);
        }
    };

#pragma unroll 1
    for (int kb = 0; kb < 15; ++kb) {
        const int cur = kb & 1, nxt = cur ^ 1;

        // issue next B-panel loads (L2) and next A loads (L3/HBM) NOW;
        // they fly under this K-step's ds_read+MFMA work.
        const short* bp = bsrc + (size_t)(kb + 1) * 8192 + tid * 8;
        bf16x8 s0 = *reinterpret_cast<const bf16x8*>(bp);
        bf16x8 s1 = *reinterpret_cast<const bf16x8*>(bp + 2048);
        bf16x8 s2 = *reinterpret_cast<const bf16x8*>(bp + 4096);
        bf16x8 s3 = *reinterpret_cast<const bf16x8*>(bp + 6144);
        float4 An0 = z4, An1 = z4, An2 = z4, An3 = z4;
        {
            const float* ap = aptr + (kb + 1) * 64;
            if (avalid) {
                An0 = *reinterpret_cast<const float4*>(ap);
                An1 = *reinterpret_cast<const float4*>(ap + 4);
                An2 = *reinterpret_cast<const float4*>(ap + 32);
                An3 = *reinterpret_cast<const float4*>(ap + 36);
            }
        }
        __builtin_amdgcn_sched_barrier(0);   // pin load-issue above the MFMA block

        const bf16x8 af0 = cvt8(Ac0, Ac1);
        const bf16x8 af1 = cvt8(Ac2, Ac3);
        compute(cur, af0, af1);

        // land staged B into next buffer (vmcnt wait sits here, after MFMAs)
        *reinterpret_cast<bf16x8*>(&Bs[nxt][tid * 8])        = s0;
        *reinterpret_cast<bf16x8*>(&Bs[nxt][2048 + tid * 8]) = s1;
        *reinterpret_cast<bf16x8*>(&Bs[nxt][4096 + tid * 8]) = s2;
        *reinterpret_cast<bf16x8*>(&Bs[nxt][6144 + tid * 8]) = s3;

        Ac0 = An0; Ac1 = An1; Ac2 = An2; Ac3 = An3;
        __syncthreads();
    }
    {   // kb = 15 (buffer 1)
        const bf16x8 af0 = cvt8(Ac0, Ac1);
        const bf16x8 af1 = cvt8(Ac2, Ac3);
        compute(1, af0, af1);
    }

    // ---- epilogue: masked softplus reduction ----
    // C/D layout: col = lane&15 (sentence), row = kgrp*4 + j (token in 16-frag)
    float ep = 0.f, en = 0.f;
#pragma unroll
    for (int n = 0; n < 8; ++n) {
        const int g = n * 16 + lrow;
#pragma unroll
        for (int j = 0; j < 4; ++j) {
            const int rl = wave * 16 + kgrp * 4 + j;   // local token row
            if (rl < count) {
                float res = acc[n][j];
                float sp  = softplus_f(res);
                if (g == b_sent) ep += res - sp;   // -softplus(-res)
                else             en += sp;         // softplus(-res)+res
            }
        }
    }

#pragma unroll
    for (int off = 32; off; off >>= 1) {
        ep += __shfl_down(ep, off);
        en += __shfl_down(en, off);
    }
    if (lane == 0) { sred[wave * 2] = ep; sred[wave * 2 + 1] = en; }
    __syncthreads();
    if (tid == 0) {
        float tep = sred[0] + sred[2] + sred[4] + sred[6];
        float ten = sred[1] + sred[3] + sred[5] + sred[7];
        atomicAdd(&acc_ws[side * 2 + 0], tep);
        atomicAdd(&acc_ws[side * 2 + 1], ten);
    }
}

__global__ void mi_finalize_kernel(const int* __restrict__ len0,
                                   const int* __restrict__ len1,
                                   const float* __restrict__ acc_ws,
                                   float* __restrict__ out)
{
    const int lane = threadIdx.x;   // 1 wave
    int s0 = 0, s1 = 0;
    for (int i = lane; i < B_SENT; i += 64) {
        s0 += max(1, len0[i]);
        s1 += max(1, len1[i]);
    }
#pragma unroll
    for (int off = 32; off; off >>= 1) {
        s0 += __shfl_down(s0, off);
        s1 += __shfl_down(s1, off);
    }
    if (lane == 0) {
        const float num_nodes = (float)(s0 + s1);
        const float ep = acc_ws[0] + acc_ws[2];
        const float en = acc_ws[1] + acc_ws[3];
        out[0] = en / (num_nodes * (float)(B_SENT - 1)) - ep / num_nodes;
        out[1] = ((float)s0 + (float)s1) / (2.0f * (float)B_SENT);
    }
}

extern "C" void kernel_launch(void* const* d_in, const int* in_sizes, int n_in,
                              void* d_out, int out_size, void* d_ws, size_t ws_size,
                              hipStream_t stream) {
    const float* tok0  = (const float*)d_in[0];
    const float* tok1  = (const float*)d_in[1];
    const float* glob0 = (const float*)d_in[2];
    const float* glob1 = (const float*)d_in[3];
    const int*   len0  = (const int*)d_in[4];
    const int*   len1  = (const int*)d_in[5];
    float* out = (float*)d_out;

    float* acc    = (float*)d_ws;                       // 4 floats @ offset 0
    short* packed = (short*)((char*)d_ws + 256);        // 512 KB bf16 fragments

    hipMemsetAsync(d_ws, 0, 256, stream);
    pack_g_kernel<<<128, 256, 0, stream>>>(glob0, glob1, packed);

    dim3 grid(32768 / TM, 2);   // 512 token-tiles x 2 sides
    mi_main_kernel<<<grid, 256, 0, stream>>>(tok0, tok1, len0, len1, packed, acc);
    mi_finalize_kernel<<<1, 64, 0, stream>>>(len0, len1, acc, out);
}